// Round 7
// baseline (551.700 us; speedup 1.0000x reference)
//
#include <hip/hip_runtime.h>
#include <stdint.h>

typedef __bf16 bf16x8 __attribute__((ext_vector_type(8)));
typedef float f32x4 __attribute__((ext_vector_type(4)));
typedef unsigned short us4 __attribute__((ext_vector_type(4)));
typedef unsigned short us8 __attribute__((ext_vector_type(8)));

#define DIMC 384
#define HEADS 8
#define BATCH 4
#define HW 16384
#define C3 1152
#define CHD 48

__device__ __forceinline__ unsigned short f2b(float f) {
  unsigned int u = __float_as_uint(f);
  u = (u + 0x7fffu + ((u >> 16) & 1u)) >> 16;
  return (unsigned short)u;
}
__device__ __forceinline__ float b2f(unsigned short h) {
  return __uint_as_float(((unsigned int)h) << 16);
}

// async global->LDS, 16B per lane; LDS dest = wave-uniform base + lane*16
__device__ __forceinline__ void glds16(const void* g, void* l) {
  __builtin_amdgcn_global_load_lds(
      (const __attribute__((address_space(1))) void*)g,
      (__attribute__((address_space(3))) void*)l, 16, 0, 0);
}

// ---------------- power iteration stage 1: t = W^T u (qkv, proj) -------------
__global__ __launch_bounds__(384) void k_wtu(
    const float* __restrict__ qkv_w, const float* __restrict__ proj_w,
    const float* __restrict__ u_qkv, const float* __restrict__ u_proj,
    float* __restrict__ t0, float* __restrict__ t2) {
  int mat = blockIdx.y;
  const float* W = mat ? proj_w : qkv_w;
  const float* u = mat ? u_proj : u_qkv;
  float* t = mat ? t2 : t0;
  int H = mat ? DIMC : C3;
  int r0 = blockIdx.x * 128;
  if (r0 >= H) return;
  int c = threadIdx.x;  // < 384, coalesced over columns
  float acc = 0.f;
  int rend = min(r0 + 128, H);
  for (int r = r0; r < rend; ++r) acc += W[(long)r * DIMC + c] * u[r];
  atomicAdd(&t[c], acc);
}

// ---------------- stage 1 for depthwise weight (1152x9) ----------------------
__global__ __launch_bounds__(256) void k_wtu_dw(
    const float* __restrict__ dw_w, const float* __restrict__ u_dw,
    float* __restrict__ t1) {
  float acc[9] = {};
  for (int r = threadIdx.x; r < C3; r += 256) {
    float ur = u_dw[r];
#pragma unroll
    for (int j = 0; j < 9; ++j) acc[j] += dw_w[r * 9 + j] * ur;
  }
  __shared__ float sh[9];
  if (threadIdx.x < 9) sh[threadIdx.x] = 0.f;
  __syncthreads();
#pragma unroll
  for (int j = 0; j < 9; ++j) atomicAdd(&sh[j], acc[j]);
  __syncthreads();
  if (threadIdx.x < 9) t1[threadIdx.x] = sh[threadIdx.x];
}

// ---------------- stage 2: sig2[mat] = |W t|^2, one wave per row -------------
__global__ __launch_bounds__(256) void k_wv(
    const float* __restrict__ qkv_w, const float* __restrict__ dw_w,
    const float* __restrict__ proj_w, const float* __restrict__ t0,
    const float* __restrict__ t1, const float* __restrict__ t2,
    float* __restrict__ sig2) {
  int mat = blockIdx.y;
  const float* W; const float* t; int H, Kc;
  if (mat == 0) { W = qkv_w; t = t0; H = C3; Kc = DIMC; }
  else if (mat == 1) { W = dw_w; t = t1; H = C3; Kc = 9; }
  else { W = proj_w; t = t2; H = DIMC; Kc = DIMC; }
  int wave = threadIdx.x >> 6, lane = threadIdx.x & 63;
  int r = blockIdx.x * 4 + wave;
  if (r >= H) return;
  float acc = 0.f;
  for (int c = lane; c < Kc; c += 64) acc += W[(long)r * Kc + c] * t[c];
  for (int off = 32; off; off >>= 1) acc += __shfl_down(acc, off);
  if (lane == 0) atomicAdd(&sig2[mat], acc * acc);
}

// ---------------- stage 3: scales[mat] = 1/(sqrt(sig2)/max(|t|,eps) + eps) ---
__global__ __launch_bounds__(256) void k_scale(
    const float* __restrict__ t0, const float* __restrict__ t1,
    const float* __restrict__ t2, const float* __restrict__ sig2,
    float* __restrict__ scales) {
  __shared__ float red[256];
  int tid = threadIdx.x;
  const float* ts[3] = {t0, t1, t2};
  const int ks[3] = {DIMC, 9, DIMC};
  for (int m = 0; m < 3; ++m) {
    float ss = 0.f;
    for (int c = tid; c < ks[m]; c += 256) ss += ts[m][c] * ts[m][c];
    red[tid] = ss; __syncthreads();
    for (int s = 128; s; s >>= 1) { if (tid < s) red[tid] += red[tid + s]; __syncthreads(); }
    if (tid == 0) {
      float tn = fmaxf(sqrtf(red[0]), 1e-12f);
      float sigma = sqrtf(sig2[m]) / tn;
      scales[m] = 1.0f / (sigma + 1e-12f);
    }
    __syncthreads();
  }
}

// ---------------- scale + convert weights -----------------------------------
__global__ __launch_bounds__(256) void k_prep(
    const float* __restrict__ qkv_w, const float* __restrict__ dw_w,
    const float* __restrict__ proj_w, const float* __restrict__ scales,
    unsigned short* __restrict__ wq, unsigned short* __restrict__ wp,
    float* __restrict__ wd) {
  int i = blockIdx.x * 256 + threadIdx.x;
  float sq = scales[0], sd = scales[1], sp = scales[2];
  if (i < C3 * DIMC) wq[i] = f2b(qkv_w[i] * sq);
  if (i < DIMC * DIMC) wp[i] = f2b(proj_w[i] * sp);
  if (i < C3 * 9) wd[i] = dw_w[i] * sd;
}

// ---------------- x (B,C,HW) fp32 -> xT (B,HW,C) bf16, vectorized stores -----
__global__ __launch_bounds__(256) void k_transpose(
    const float* __restrict__ x, unsigned short* __restrict__ xT) {
  __shared__ float tile[64][33];
  int b = blockIdx.z;
  int c0 = blockIdx.y * 64, n0 = blockIdx.x * 32;
  int tid = threadIdx.x;
  const float* xb = x + (long)b * DIMC * HW;
  int rr = tid >> 5, cc = tid & 31;
#pragma unroll
  for (int it = 0; it < 8; ++it)
    tile[it * 8 + rr][cc] = xb[(long)(c0 + it * 8 + rr) * HW + n0 + cc];
  __syncthreads();
  unsigned short* xTb = xT + (long)b * HW * DIMC;
  int j = tid >> 3, cq = (tid & 7) * 8;
  us8 st;
#pragma unroll
  for (int u = 0; u < 8; ++u) st[u] = f2b(tile[cq + u][j]);
  *(us8*)(xTb + (long)(n0 + j) * DIMC + c0 + cq) = st;
}

// ---------------- 128x128 bf16 MFMA GEMM, counted-vmcnt pipeline (T3+T4) -----
// C = A(Mx384) * BT(Nx384)^T. 4 waves (2x2), per-wave 64x64 out. BK=32.
// 3 LDS buffers (48 KiB, 3 blocks/CU), stages 2-deep in flight. Per K-step:
// s_waitcnt vmcnt(4) (tile t landed; tile t+1's 4 DMAs stay in flight) + ONE
// raw s_barrier. NEVER vmcnt(0) in the loop (r6 lesson: __syncthreads drains
// the prefetch every step -> no pipeline; MfmaUtil pinned at 27%).
// Race-safety: stage(t+2) issued AFTER the barrier, so buf[(t+2)%3]'s
// iter-(t-1) readers are provably done. sched_barrier(0) pins ds_reads below
// the barrier (compiler can't see DMA->LDS deps).
template <bool BF16_OUT>
__global__ __launch_bounds__(256, 3) void gemm128(
    const unsigned short* __restrict__ A, const unsigned short* __restrict__ BT,
    void* __restrict__ Cv, long sB, long sC) {
  __shared__ __align__(16) unsigned short lds[3][2][128][32];  // 48 KiB
  const int tid = threadIdx.x;
  const int wave = tid >> 6, lane = tid & 63;
  const int wm = (wave >> 1) * 64, wn = (wave & 1) * 64;
  const int qm = lane & 15, kq = lane >> 4;
  const int m0 = blockIdx.y * 128, n0 = blockIdx.x * 128;
  const unsigned short* Bb = BT + (long)blockIdx.z * sB;

  auto stage = [&](int ks, int d) {  // 4 glds16 per thread per stage
    const int kb = ks * 32;
    unsigned short* LA = &lds[d][0][0][0];
    unsigned short* LB = &lds[d][1][0][0];
#pragma unroll
    for (int i = 0; i < 2; ++i) {
      int c = tid + i * 256;          // 16B-chunk index, 0..511
      int row = c >> 2, j = c & 3;
      int g = (j ^ ((row >> 1) & 3)) * 8;  // inverse swizzle on global source
      glds16(A + (long)(m0 + row) * 384 + kb + g, LA + c * 8);
      glds16(Bb + (long)(n0 + row) * 384 + kb + g, LB + c * 8);
    }
  };

  f32x4 acc[4][4] = {};
  stage(0, 0);
  stage(1, 1);

#pragma unroll
  for (int t = 0; t < 12; ++t) {
    if (t < 11) asm volatile("s_waitcnt vmcnt(4)" ::: "memory");
    else        asm volatile("s_waitcnt vmcnt(0)" ::: "memory");
    __builtin_amdgcn_s_barrier();
    __builtin_amdgcn_sched_barrier(0);
    if (t + 2 < 12) stage(t + 2, (t + 2) % 3);
    const char* At = (const char*)&lds[t % 3][0][0][0];
    const char* Bt = (const char*)&lds[t % 3][1][0][0];
    bf16x8 av[4], bv[4];
#pragma unroll
    for (int mi = 0; mi < 4; ++mi) {
      int ra = wm + mi * 16 + qm;
      av[mi] = *(const bf16x8*)(At + ra * 64 + ((kq ^ ((ra >> 1) & 3)) << 4));
      int rb = wn + mi * 16 + qm;
      bv[mi] = *(const bf16x8*)(Bt + rb * 64 + ((kq ^ ((rb >> 1) & 3)) << 4));
    }
    __builtin_amdgcn_s_setprio(1);
#pragma unroll
    for (int mi = 0; mi < 4; ++mi)
#pragma unroll
      for (int ni = 0; ni < 4; ++ni)
        acc[mi][ni] = __builtin_amdgcn_mfma_f32_16x16x32_bf16(
            av[mi], bv[ni], acc[mi][ni], 0, 0, 0);
    __builtin_amdgcn_s_setprio(0);
  }

  const int col = lane & 15, rowq = (lane >> 4) * 4;
  if (BF16_OUT) {
    unsigned short* Cb = (unsigned short*)Cv + (long)blockIdx.z * sC;
#pragma unroll
    for (int mi = 0; mi < 4; ++mi)
#pragma unroll
      for (int ni = 0; ni < 4; ++ni) {
        int m = m0 + wm + mi * 16 + rowq;
        int n = n0 + wn + ni * 16 + col;
#pragma unroll
        for (int r = 0; r < 4; ++r)
          Cb[(long)(m + r) * 16384 + n] = f2b(acc[mi][ni][r]);
      }
  } else {
    float* Cb = (float*)Cv + (long)blockIdx.z * sC;
#pragma unroll
    for (int mi = 0; mi < 4; ++mi)
#pragma unroll
      for (int ni = 0; ni < 4; ++ni) {
        int m = m0 + wm + mi * 16 + rowq;
        int n = n0 + wn + ni * 16 + col;
#pragma unroll
        for (int r = 0; r < 4; ++r)
          Cb[(long)(m + r) * 16384 + n] = acc[mi][ni][r];
      }
  }
}

// ---------------- depthwise 3x3 (SAME) + sumsq, sliding-window ---------------
__global__ __launch_bounds__(256) void k_dwconv(
    const unsigned short* __restrict__ qkv, const float* __restrict__ wd,
    unsigned short* __restrict__ out, float* __restrict__ sumsq) {
  int c = blockIdx.x, b = blockIdx.y;
  const unsigned short* in = qkv + ((long)b * C3 + c) * HW;
  unsigned short* o = out + ((long)b * C3 + c) * HW;
  float w[9];
#pragma unroll
  for (int i = 0; i < 9; ++i) w[i] = wd[c * 9 + i];
  int tid = threadIdx.x;
  int s = tid & 15, g = tid >> 4;
  int r0 = g * 8, x0 = s * 8;

  uint4 raw[10];
  const uint4 z4 = {0u, 0u, 0u, 0u};
#pragma unroll
  for (int i = 0; i < 10; ++i) {
    int yy = r0 - 1 + i;
    raw[i] = (yy >= 0 && yy < 128) ? *(const uint4*)(in + yy * 128 + x0) : z4;
  }

  float win[3][10];
  auto unpack = [&](uint4 pk, float* a) {
    a[1] = __uint_as_float(pk.x << 16);
    a[2] = __uint_as_float(pk.x & 0xffff0000u);
    a[3] = __uint_as_float(pk.y << 16);
    a[4] = __uint_as_float(pk.y & 0xffff0000u);
    a[5] = __uint_as_float(pk.z << 16);
    a[6] = __uint_as_float(pk.z & 0xffff0000u);
    a[7] = __uint_as_float(pk.w << 16);
    a[8] = __uint_as_float(pk.w & 0xffff0000u);
    float lv = __shfl_up(a[8], 1);
    float rv = __shfl_down(a[1], 1);
    a[0] = (s == 0) ? 0.f : lv;
    a[9] = (s == 15) ? 0.f : rv;
  };
  unpack(raw[0], win[0]);
  unpack(raw[1], win[1]);

  float ss = 0.f;
#pragma unroll
  for (int i = 0; i < 8; ++i) {
    unpack(raw[i + 2], win[(i + 2) % 3]);
    const float* tp = win[i % 3];
    const float* md = win[(i + 1) % 3];
    const float* bt = win[(i + 2) % 3];
    us8 st;
#pragma unroll
    for (int j = 0; j < 8; ++j) {
      float acc = w[0] * tp[j] + w[1] * tp[j + 1] + w[2] * tp[j + 2]
                + w[3] * md[j] + w[4] * md[j + 1] + w[5] * md[j + 2]
                + w[6] * bt[j] + w[7] * bt[j + 1] + w[8] * bt[j + 2];
      unsigned short ob = f2b(acc);
      st[j] = ob;
      float av = b2f(ob);
      ss += av * av;
    }
    *(us8*)(o + (r0 + i) * 128 + x0) = st;
  }
  if (c < 2 * DIMC) {
#pragma unroll
    for (int off = 32; off; off >>= 1) ss += __shfl_down(ss, off);
    if ((tid & 63) == 0) atomicAdd(&sumsq[b * 2 * DIMC + c], ss);
  }
}

// ---------------- S = Q K^T (unnormalized) -----------------------------------
__global__ __launch_bounds__(256) void k_qk(
    const unsigned short* __restrict__ dwo, float* __restrict__ S) {
  int bh = blockIdx.y, b = bh >> 3, h = bh & 7;
  int wave = threadIdx.x >> 6, lane = threadIdx.x & 63;
  int fm = lane & 15, fk = (lane >> 4) * 8;
  long kbase = (long)(blockIdx.x * 4 + wave) * 128;
  const unsigned short* Q = dwo + ((long)b * C3 + h * CHD) * HW;
  const unsigned short* Km = dwo + ((long)b * C3 + DIMC + h * CHD) * HW;
  const unsigned short* qr = Q + (long)fm * HW + kbase + fk;
  const unsigned short* kr = Km + (long)fm * HW + kbase + fk;
  f32x4 acc[3][3] = {};
#pragma unroll
  for (int k = 0; k < 128; k += 32) {
    bf16x8 a[3], bv[3];
#pragma unroll
    for (int t = 0; t < 3; ++t) {
      a[t] = *(const bf16x8*)(qr + (long)t * 16 * HW + k);
      bv[t] = *(const bf16x8*)(kr + (long)t * 16 * HW + k);
    }
#pragma unroll
    for (int mi = 0; mi < 3; ++mi)
#pragma unroll
      for (int ni = 0; ni < 3; ++ni)
        acc[mi][ni] = __builtin_amdgcn_mfma_f32_16x16x32_bf16(a[mi], bv[ni], acc[mi][ni], 0, 0, 0);
  }
  __shared__ float red[4][64][37];  // 37: odd stride, bank-conflict-free
#pragma unroll
  for (int mi = 0; mi < 3; ++mi)
#pragma unroll
    for (int ni = 0; ni < 3; ++ni)
#pragma unroll
      for (int r = 0; r < 4; ++r)
        red[wave][lane][mi * 12 + ni * 4 + r] = acc[mi][ni][r];
  __syncthreads();
  int l2 = threadIdx.x & 63, g = threadIdx.x >> 6;
  float* Sb = S + (long)bh * CHD * CHD;
#pragma unroll
  for (int ii = 0; ii < 9; ++ii) {
    int i = g * 9 + ii;
    float v = red[0][l2][i] + red[1][l2][i] + red[2][l2][i] + red[3][l2][i];
    int mi = i / 12, ni = (i % 12) / 4, r = i & 3;
    int row = mi * 16 + ((l2 >> 4) << 2) + r;
    int col = ni * 16 + (l2 & 15);
    atomicAdd(&Sb[row * CHD + col], v);
  }
}

// ---------------- normalize + temp + clamp + softmax -> P bf16 (48x64) -------
__global__ __launch_bounds__(256) void k_softmax(
    const float* __restrict__ S, const float* __restrict__ sumsq,
    const float* __restrict__ temperature, unsigned short* __restrict__ P) {
  int bh = blockIdx.y, b = bh >> 3, h = bh & 7;
  int wave = threadIdx.x >> 6, lane = threadIdx.x & 63;
  int i = blockIdx.x * 4 + wave;  // row 0..47
  float t = temperature[h];
  const float* Sb = S + (long)bh * CHD * CHD;
  const float* nq = sumsq + b * 2 * DIMC + h * CHD;
  const float* nk = sumsq + b * 2 * DIMC + DIMC + h * CHD;
  unsigned short* Pb = P + (long)bh * CHD * 64;
  float qn = fmaxf(sqrtf(nq[i]), 1e-12f);
  float v = -1e30f;
  if (lane < CHD) {
    float kn = fmaxf(sqrtf(nk[lane]), 1e-12f);
    v = Sb[i * CHD + lane] / (qn * kn) * t;
    v = fminf(fmaxf(v, -50.f), 50.f);
  }
  float mx = v;
#pragma unroll
  for (int off = 32; off; off >>= 1) mx = fmaxf(mx, __shfl_xor(mx, off));
  float e = (lane < CHD) ? __expf(v - mx) : 0.f;
  float sum = e;
#pragma unroll
  for (int off = 32; off; off >>= 1) sum += __shfl_xor(sum, off);
  Pb[i * 64 + lane] = f2b(e / sum);
}

// ---------------- O^T = (P @ V)^T, bf16, (B, HW, 384) ------------------------
__global__ __launch_bounds__(256) void k_pv(
    const unsigned short* __restrict__ P, const unsigned short* __restrict__ dwo,
    unsigned short* __restrict__ OT) {
  int bh = blockIdx.y, b = bh >> 3, h = bh & 7;
  int wave = threadIdx.x >> 6, lane = threadIdx.x & 63;
  int fm = lane & 15, fq = lane >> 4;
  const unsigned short* Pb = P + (long)bh * CHD * 64;
  const unsigned short* V = dwo + ((long)b * C3 + 2 * DIMC + h * CHD) * HW;
  bf16x8 a0[3], a1[3];
#pragma unroll
  for (int t = 0; t < 3; ++t) {
    a0[t] = *(const bf16x8*)(Pb + (t * 16 + fm) * 64 + fq * 8);
    a1[t] = *(const bf16x8*)(Pb + (t * 16 + fm) * 64 + 32 + fq * 8);
  }
  unsigned short* OTb = OT + (long)b * HW * DIMC;
  for (int nt = 0; nt < 4; ++nt) {
    int n0 = (blockIdx.x * 16 + wave * 4 + nt) * 16;
    bf16x8 b0, b1;
#pragma unroll
    for (int j = 0; j < 8; ++j) {
      int kk0 = fq * 8 + j;
      ((__bf16*)&b0)[j] = *(const __bf16*)(V + (long)kk0 * HW + n0 + fm);
      int kk1 = 32 + fq * 8 + j;
      ((__bf16*)&b1)[j] = (kk1 < CHD) ? *(const __bf16*)(V + (long)kk1 * HW + n0 + fm)
                                      : (__bf16)0.0f;
    }
    f32x4 acc[3] = {};
#pragma unroll
    for (int t = 0; t < 3; ++t) {
      acc[t] = __builtin_amdgcn_mfma_f32_16x16x32_bf16(a0[t], b0, acc[t], 0, 0, 0);
      acc[t] = __builtin_amdgcn_mfma_f32_16x16x32_bf16(a1[t], b1, acc[t], 0, 0, 0);
    }
    int n = n0 + fm;
#pragma unroll
    for (int t = 0; t < 3; ++t) {
      int cg = h * CHD + t * 16 + fq * 4;
      us4 st;
#pragma unroll
      for (int r = 0; r < 4; ++r) st[r] = f2b(acc[t][r]);
      *(us4*)(OTb + (long)n * DIMC + cg) = st;
    }
  }
}

extern "C" void kernel_launch(void* const* d_in, const int* in_sizes, int n_in,
                              void* d_out, int out_size, void* d_ws, size_t ws_size,
                              hipStream_t stream) {
  const float* x = (const float*)d_in[0];
  const float* qkv_w = (const float*)d_in[1];
  const float* dw_w = (const float*)d_in[2];
  const float* proj_w = (const float*)d_in[3];
  const float* temp = (const float*)d_in[4];
  const float* u_qkv = (const float*)d_in[5];
  const float* u_dw = (const float*)d_in[6];
  const float* u_proj = (const float*)d_in[7];
  float* out = (float*)d_out;

  char* ws = (char*)d_ws;
  size_t cur = 0;
  auto take = [&](size_t n) { size_t r = cur; cur += (n + 255) & ~(size_t)255; return r; };
  // power-iteration scratch: t0 | t1 | t2 | sig2 contiguous -> one memset
  float* t0 = (float*)(ws + take(DIMC * 4));        // 384
  float* t1 = (float*)(ws + take(16 * 4));          // 9 (padded)
  float* t2 = (float*)(ws + take(DIMC * 4));        // 384
  float* sig2 = (float*)(ws + take(4 * 4));         // 3
  size_t tbytes = cur;                              // all of the above
  float* scales = (float*)(ws + take(3 * 4));
  float* sumsq = (float*)(ws + take((size_t)BATCH * 2 * DIMC * 4));
  float* S = (float*)(ws + take((size_t)32 * CHD * CHD * 4));
  unsigned short* P = (unsigned short*)(ws + take((size_t)32 * CHD * 64 * 2));
  unsigned short* wq = (unsigned short*)(ws + take((size_t)C3 * DIMC * 2));
  unsigned short* wp = (unsigned short*)(ws + take((size_t)DIMC * DIMC * 2));
  float* wd = (float*)(ws + take((size_t)C3 * 9 * 4));
  unsigned short* xT = (unsigned short*)(ws + take((size_t)BATCH * HW * DIMC * 2));
  unsigned short* qkv = (unsigned short*)(ws + take((size_t)BATCH * C3 * HW * 2));
  unsigned short* dwo = (unsigned short*)(ws + take((size_t)BATCH * C3 * HW * 2));
  unsigned short* OT = xT;  // xT is dead after gemm1; reuse for O^T

  hipMemsetAsync(ws, 0, tbytes, stream);  // t0,t1,t2,sig2
  hipMemsetAsync(sumsq, 0, (size_t)BATCH * 2 * DIMC * 4, stream);
  hipMemsetAsync(S, 0, (size_t)32 * CHD * CHD * 4, stream);

  k_wtu<<<dim3(9, 2), dim3(384), 0, stream>>>(qkv_w, proj_w, u_qkv, u_proj, t0, t2);
  k_wtu_dw<<<dim3(1), dim3(256), 0, stream>>>(dw_w, u_dw, t1);
  k_wv<<<dim3(288, 3), dim3(256), 0, stream>>>(qkv_w, dw_w, proj_w, t0, t1, t2, sig2);
  k_scale<<<dim3(1), dim3(256), 0, stream>>>(t0, t1, t2, sig2, scales);
  k_prep<<<dim3((C3 * DIMC + 255) / 256), dim3(256), 0, stream>>>(qkv_w, dw_w, proj_w, scales, wq, wp, wd);
  k_transpose<<<dim3(HW / 32, DIMC / 64, BATCH), dim3(256), 0, stream>>>(x, xT);
  gemm128<true><<<dim3(HW / 128, C3 / 128, BATCH), dim3(256), 0, stream>>>(
      wq, xT, qkv, (long)HW * DIMC, (long)C3 * HW);
  k_dwconv<<<dim3(C3, BATCH), dim3(256), 0, stream>>>(qkv, wd, dwo, sumsq);
  k_qk<<<dim3(32, 32), dim3(256), 0, stream>>>(dwo, S);
  k_softmax<<<dim3(12, 32), dim3(256), 0, stream>>>(S, sumsq, temp, P);
  k_pv<<<dim3(64, 32), dim3(256), 0, stream>>>(P, dwo, OT);
  gemm128<false><<<dim3(HW / 128, DIMC / 128, BATCH), dim3(256), 0, stream>>>(
      wp, OT, out, (long)HW * DIMC, (long)DIMC * HW);
}

// Round 9
// 543.768 us; speedup vs baseline: 1.0146x; 1.0146x over previous
//
#include <hip/hip_runtime.h>
#include <stdint.h>

typedef __bf16 bf16x8 __attribute__((ext_vector_type(8)));
typedef float f32x4 __attribute__((ext_vector_type(4)));
typedef unsigned short us4 __attribute__((ext_vector_type(4)));
typedef unsigned short us8 __attribute__((ext_vector_type(8)));

#define DIMC 384
#define HEADS 8
#define BATCH 4
#define HW 16384
#define C3 1152
#define CHD 48

__device__ __forceinline__ unsigned short f2b(float f) {
  unsigned int u = __float_as_uint(f);
  u = (u + 0x7fffu + ((u >> 16) & 1u)) >> 16;
  return (unsigned short)u;
}
__device__ __forceinline__ float b2f(unsigned short h) {
  return __uint_as_float(((unsigned int)h) << 16);
}

// async global->LDS, 16B per lane; LDS dest = wave-uniform base + lane*16
__device__ __forceinline__ void glds16(const void* g, void* l) {
  __builtin_amdgcn_global_load_lds(
      (const __attribute__((address_space(1))) void*)g,
      (__attribute__((address_space(3))) void*)l, 16, 0, 0);
}

// ---------------- power iteration stage 1: t = W^T u (qkv, proj) -------------
__global__ __launch_bounds__(384) void k_wtu(
    const float* __restrict__ qkv_w, const float* __restrict__ proj_w,
    const float* __restrict__ u_qkv, const float* __restrict__ u_proj,
    float* __restrict__ t0, float* __restrict__ t2) {
  int mat = blockIdx.y;
  const float* W = mat ? proj_w : qkv_w;
  const float* u = mat ? u_proj : u_qkv;
  float* t = mat ? t2 : t0;
  int H = mat ? DIMC : C3;
  int r0 = blockIdx.x * 128;
  if (r0 >= H) return;
  int c = threadIdx.x;  // < 384, coalesced over columns
  float acc = 0.f;
  int rend = min(r0 + 128, H);
  for (int r = r0; r < rend; ++r) acc += W[(long)r * DIMC + c] * u[r];
  atomicAdd(&t[c], acc);
}

// ---------------- stage 1 for depthwise weight (1152x9) ----------------------
__global__ __launch_bounds__(256) void k_wtu_dw(
    const float* __restrict__ dw_w, const float* __restrict__ u_dw,
    float* __restrict__ t1) {
  float acc[9] = {};
  for (int r = threadIdx.x; r < C3; r += 256) {
    float ur = u_dw[r];
#pragma unroll
    for (int j = 0; j < 9; ++j) acc[j] += dw_w[r * 9 + j] * ur;
  }
  __shared__ float sh[9];
  if (threadIdx.x < 9) sh[threadIdx.x] = 0.f;
  __syncthreads();
#pragma unroll
  for (int j = 0; j < 9; ++j) atomicAdd(&sh[j], acc[j]);
  __syncthreads();
  if (threadIdx.x < 9) t1[threadIdx.x] = sh[threadIdx.x];
}

// ---------------- stage 2: sig2[mat] = |W t|^2, one wave per row -------------
__global__ __launch_bounds__(256) void k_wv(
    const float* __restrict__ qkv_w, const float* __restrict__ dw_w,
    const float* __restrict__ proj_w, const float* __restrict__ t0,
    const float* __restrict__ t1, const float* __restrict__ t2,
    float* __restrict__ sig2) {
  int mat = blockIdx.y;
  const float* W; const float* t; int H, Kc;
  if (mat == 0) { W = qkv_w; t = t0; H = C3; Kc = DIMC; }
  else if (mat == 1) { W = dw_w; t = t1; H = C3; Kc = 9; }
  else { W = proj_w; t = t2; H = DIMC; Kc = DIMC; }
  int wave = threadIdx.x >> 6, lane = threadIdx.x & 63;
  int r = blockIdx.x * 4 + wave;
  if (r >= H) return;
  float acc = 0.f;
  for (int c = lane; c < Kc; c += 64) acc += W[(long)r * Kc + c] * t[c];
  for (int off = 32; off; off >>= 1) acc += __shfl_down(acc, off);
  if (lane == 0) atomicAdd(&sig2[mat], acc * acc);
}

// ---------------- stage 3: scales[mat] = 1/(sqrt(sig2)/max(|t|,eps) + eps) ---
__global__ __launch_bounds__(256) void k_scale(
    const float* __restrict__ t0, const float* __restrict__ t1,
    const float* __restrict__ t2, const float* __restrict__ sig2,
    float* __restrict__ scales) {
  __shared__ float red[256];
  int tid = threadIdx.x;
  const float* ts[3] = {t0, t1, t2};
  const int ks[3] = {DIMC, 9, DIMC};
  for (int m = 0; m < 3; ++m) {
    float ss = 0.f;
    for (int c = tid; c < ks[m]; c += 256) ss += ts[m][c] * ts[m][c];
    red[tid] = ss; __syncthreads();
    for (int s = 128; s; s >>= 1) { if (tid < s) red[tid] += red[tid + s]; __syncthreads(); }
    if (tid == 0) {
      float tn = fmaxf(sqrtf(red[0]), 1e-12f);
      float sigma = sqrtf(sig2[m]) / tn;
      scales[m] = 1.0f / (sigma + 1e-12f);
    }
    __syncthreads();
  }
}

// ---------------- scale + convert weights -----------------------------------
__global__ __launch_bounds__(256) void k_prep(
    const float* __restrict__ qkv_w, const float* __restrict__ dw_w,
    const float* __restrict__ proj_w, const float* __restrict__ scales,
    unsigned short* __restrict__ wq, unsigned short* __restrict__ wp,
    float* __restrict__ wd) {
  int i = blockIdx.x * 256 + threadIdx.x;
  float sq = scales[0], sd = scales[1], sp = scales[2];
  if (i < C3 * DIMC) wq[i] = f2b(qkv_w[i] * sq);
  if (i < DIMC * DIMC) wp[i] = f2b(proj_w[i] * sp);
  if (i < C3 * 9) wd[i] = dw_w[i] * sd;
}

// ---------------- x (B,C,HW) fp32 -> xT (B,HW,C) bf16, vectorized stores -----
__global__ __launch_bounds__(256) void k_transpose(
    const float* __restrict__ x, unsigned short* __restrict__ xT) {
  __shared__ float tile[64][33];
  int b = blockIdx.z;
  int c0 = blockIdx.y * 64, n0 = blockIdx.x * 32;
  int tid = threadIdx.x;
  const float* xb = x + (long)b * DIMC * HW;
  int rr = tid >> 5, cc = tid & 31;
#pragma unroll
  for (int it = 0; it < 8; ++it)
    tile[it * 8 + rr][cc] = xb[(long)(c0 + it * 8 + rr) * HW + n0 + cc];
  __syncthreads();
  unsigned short* xTb = xT + (long)b * HW * DIMC;
  int j = tid >> 3, cq = (tid & 7) * 8;
  us8 st;
#pragma unroll
  for (int u = 0; u < 8; ++u) st[u] = f2b(tile[cq + u][j]);
  *(us8*)(xTb + (long)(n0 + j) * DIMC + c0 + cq) = st;
}

// ---------------- 128x128 double-buffered bf16 MFMA GEMM (r4 structure) ------
// Best measured variant (87.4 us): BK=64, 2 buffers, drain+barrier, 64 KiB
// LDS -> 2 blocks/CU, natural block order (no XCD swizzle). Structural tests
// (BK=32 5-blk r6, counted-vmcnt 3-buf r7) were 90-97: LDS-port/shape-bound.
template <bool BF16_OUT>
__global__ __launch_bounds__(256, 2) void gemm128(
    const unsigned short* __restrict__ A, const unsigned short* __restrict__ BT,
    void* __restrict__ Cv, long sB, long sC) {
  __shared__ __align__(16) unsigned short lds[2][2][128][64];  // 64 KiB
  const int tid = threadIdx.x;
  const int wave = tid >> 6, lane = tid & 63;
  const int wm = (wave >> 1) * 64, wn = (wave & 1) * 64;
  const int qm = lane & 15, kq = lane >> 4;
  const int m0 = blockIdx.y * 128, n0 = blockIdx.x * 128;
  const unsigned short* Bb = BT + (long)blockIdx.z * sB;

  auto stage = [&](int ks, int d) {
    const int kb = ks * 64;
    unsigned short* LA = &lds[d][0][0][0];
    unsigned short* LB = &lds[d][1][0][0];
#pragma unroll
    for (int i = 0; i < 4; ++i) {
      int c = tid + i * 256;          // 16B-chunk index, 0..1023
      int row = c >> 3, j = c & 7;
      int g = (j ^ (row & 7)) * 8;    // inverse swizzle on global source
      glds16(A + (long)(m0 + row) * 384 + kb + g, LA + c * 8);
      glds16(Bb + (long)(n0 + row) * 384 + kb + g, LB + c * 8);
    }
  };

  f32x4 acc[4][4] = {};
  stage(0, 0);
  __syncthreads();

  for (int t = 0; t < 6; ++t) {
    if (t < 5) stage(t + 1, (t + 1) & 1);
    const char* At = (const char*)&lds[t & 1][0][0][0];
    const char* Bt = (const char*)&lds[t & 1][1][0][0];
    bf16x8 av[4][2], bv[4][2];
#pragma unroll
    for (int mi = 0; mi < 4; ++mi)
#pragma unroll
      for (int s = 0; s < 2; ++s) {
        int ra = wm + mi * 16 + qm, sl = kq + 4 * s;
        av[mi][s] = *(const bf16x8*)(At + ra * 128 + ((sl ^ (ra & 7)) << 4));
        int rb = wn + mi * 16 + qm;
        bv[mi][s] = *(const bf16x8*)(Bt + rb * 128 + ((sl ^ (rb & 7)) << 4));
      }
    __builtin_amdgcn_s_setprio(1);
#pragma unroll
    for (int mi = 0; mi < 4; ++mi)
#pragma unroll
      for (int ni = 0; ni < 4; ++ni)
#pragma unroll
        for (int s = 0; s < 2; ++s)
          acc[mi][ni] = __builtin_amdgcn_mfma_f32_16x16x32_bf16(
              av[mi][s], bv[ni][s], acc[mi][ni], 0, 0, 0);
    __builtin_amdgcn_s_setprio(0);
    __syncthreads();
  }

  const int col = lane & 15, rowq = (lane >> 4) * 4;
  if (BF16_OUT) {
    unsigned short* Cb = (unsigned short*)Cv + (long)blockIdx.z * sC;
#pragma unroll
    for (int mi = 0; mi < 4; ++mi)
#pragma unroll
      for (int ni = 0; ni < 4; ++ni) {
        int m = m0 + wm + mi * 16 + rowq;
        int n = n0 + wn + ni * 16 + col;
#pragma unroll
        for (int r = 0; r < 4; ++r)
          Cb[(long)(m + r) * 16384 + n] = f2b(acc[mi][ni][r]);
      }
  } else {
    float* Cb = (float*)Cv + (long)blockIdx.z * sC;
#pragma unroll
    for (int mi = 0; mi < 4; ++mi)
#pragma unroll
      for (int ni = 0; ni < 4; ++ni) {
        int m = m0 + wm + mi * 16 + rowq;
        int n = n0 + wn + ni * 16 + col;
#pragma unroll
        for (int r = 0; r < 4; ++r)
          Cb[(long)(m + r) * 16384 + n] = acc[mi][ni][r];
      }
  }
}

// ---------------- depthwise 3x3 (SAME) + sumsq, sliding-window ---------------
__global__ __launch_bounds__(256) void k_dwconv(
    const unsigned short* __restrict__ qkv, const float* __restrict__ wd,
    unsigned short* __restrict__ out, float* __restrict__ sumsq) {
  int c = blockIdx.x, b = blockIdx.y;
  const unsigned short* in = qkv + ((long)b * C3 + c) * HW;
  unsigned short* o = out + ((long)b * C3 + c) * HW;
  float w[9];
#pragma unroll
  for (int i = 0; i < 9; ++i) w[i] = wd[c * 9 + i];
  int tid = threadIdx.x;
  int s = tid & 15, g = tid >> 4;
  int r0 = g * 8, x0 = s * 8;

  uint4 raw[10];
  const uint4 z4 = {0u, 0u, 0u, 0u};
#pragma unroll
  for (int i = 0; i < 10; ++i) {
    int yy = r0 - 1 + i;
    raw[i] = (yy >= 0 && yy < 128) ? *(const uint4*)(in + yy * 128 + x0) : z4;
  }

  float win[3][10];
  auto unpack = [&](uint4 pk, float* a) {
    a[1] = __uint_as_float(pk.x << 16);
    a[2] = __uint_as_float(pk.x & 0xffff0000u);
    a[3] = __uint_as_float(pk.y << 16);
    a[4] = __uint_as_float(pk.y & 0xffff0000u);
    a[5] = __uint_as_float(pk.z << 16);
    a[6] = __uint_as_float(pk.z & 0xffff0000u);
    a[7] = __uint_as_float(pk.w << 16);
    a[8] = __uint_as_float(pk.w & 0xffff0000u);
    float lv = __shfl_up(a[8], 1);
    float rv = __shfl_down(a[1], 1);
    a[0] = (s == 0) ? 0.f : lv;
    a[9] = (s == 15) ? 0.f : rv;
  };
  unpack(raw[0], win[0]);
  unpack(raw[1], win[1]);

  float ss = 0.f;
#pragma unroll
  for (int i = 0; i < 8; ++i) {
    unpack(raw[i + 2], win[(i + 2) % 3]);
    const float* tp = win[i % 3];
    const float* md = win[(i + 1) % 3];
    const float* bt = win[(i + 2) % 3];
    us8 st;
#pragma unroll
    for (int j = 0; j < 8; ++j) {
      float acc = w[0] * tp[j] + w[1] * tp[j + 1] + w[2] * tp[j + 2]
                + w[3] * md[j] + w[4] * md[j + 1] + w[5] * md[j + 2]
                + w[6] * bt[j] + w[7] * bt[j + 1] + w[8] * bt[j + 2];
      unsigned short ob = f2b(acc);
      st[j] = ob;
      float av = b2f(ob);
      ss += av * av;
    }
    *(us8*)(o + (r0 + i) * 128 + x0) = st;
  }
  if (c < 2 * DIMC) {
#pragma unroll
    for (int off = 32; off; off >>= 1) ss += __shfl_down(ss, off);
    if ((tid & 63) == 0) atomicAdd(&sumsq[b * 2 * DIMC + c], ss);
  }
}

// ---------------- S = Q K^T (unnormalized) -----------------------------------
__global__ __launch_bounds__(256) void k_qk(
    const unsigned short* __restrict__ dwo, float* __restrict__ S) {
  int bh = blockIdx.y, b = bh >> 3, h = bh & 7;
  int wave = threadIdx.x >> 6, lane = threadIdx.x & 63;
  int fm = lane & 15, fk = (lane >> 4) * 8;
  long kbase = (long)(blockIdx.x * 4 + wave) * 128;
  const unsigned short* Q = dwo + ((long)b * C3 + h * CHD) * HW;
  const unsigned short* Km = dwo + ((long)b * C3 + DIMC + h * CHD) * HW;
  const unsigned short* qr = Q + (long)fm * HW + kbase + fk;
  const unsigned short* kr = Km + (long)fm * HW + kbase + fk;
  f32x4 acc[3][3] = {};
#pragma unroll
  for (int k = 0; k < 128; k += 32) {
    bf16x8 a[3], bv[3];
#pragma unroll
    for (int t = 0; t < 3; ++t) {
      a[t] = *(const bf16x8*)(qr + (long)t * 16 * HW + k);
      bv[t] = *(const bf16x8*)(kr + (long)t * 16 * HW + k);
    }
#pragma unroll
    for (int mi = 0; mi < 3; ++mi)
#pragma unroll
      for (int ni = 0; ni < 3; ++ni)
        acc[mi][ni] = __builtin_amdgcn_mfma_f32_16x16x32_bf16(a[mi], bv[ni], acc[mi][ni], 0, 0, 0);
  }
  __shared__ float red[4][64][37];  // 37: odd stride, bank-conflict-free
#pragma unroll
  for (int mi = 0; mi < 3; ++mi)
#pragma unroll
    for (int ni = 0; ni < 3; ++ni)
#pragma unroll
      for (int r = 0; r < 4; ++r)
        red[wave][lane][mi * 12 + ni * 4 + r] = acc[mi][ni][r];
  __syncthreads();
  int l2 = threadIdx.x & 63, g = threadIdx.x >> 6;
  float* Sb = S + (long)bh * CHD * CHD;
#pragma unroll
  for (int ii = 0; ii < 9; ++ii) {
    int i = g * 9 + ii;
    float v = red[0][l2][i] + red[1][l2][i] + red[2][l2][i] + red[3][l2][i];
    int mi = i / 12, ni = (i % 12) / 4, r = i & 3;
    int row = mi * 16 + ((l2 >> 4) << 2) + r;
    int col = ni * 16 + (l2 & 15);
    atomicAdd(&Sb[row * CHD + col], v);
  }
}

// ---------------- normalize + temp + clamp + softmax -> P bf16 (48x64) -------
__global__ __launch_bounds__(256) void k_softmax(
    const float* __restrict__ S, const float* __restrict__ sumsq,
    const float* __restrict__ temperature, unsigned short* __restrict__ P) {
  int bh = blockIdx.y, b = bh >> 3, h = bh & 7;
  int wave = threadIdx.x >> 6, lane = threadIdx.x & 63;
  int i = blockIdx.x * 4 + wave;  // row 0..47
  float t = temperature[h];
  const float* Sb = S + (long)bh * CHD * CHD;
  const float* nq = sumsq + b * 2 * DIMC + h * CHD;
  const float* nk = sumsq + b * 2 * DIMC + DIMC + h * CHD;
  unsigned short* Pb = P + (long)bh * CHD * 64;
  float qn = fmaxf(sqrtf(nq[i]), 1e-12f);
  float v = -1e30f;
  if (lane < CHD) {
    float kn = fmaxf(sqrtf(nk[lane]), 1e-12f);
    v = Sb[i * CHD + lane] / (qn * kn) * t;
    v = fminf(fmaxf(v, -50.f), 50.f);
  }
  float mx = v;
#pragma unroll
  for (int off = 32; off; off >>= 1) mx = fmaxf(mx, __shfl_xor(mx, off));
  float e = (lane < CHD) ? __expf(v - mx) : 0.f;
  float sum = e;
#pragma unroll
  for (int off = 32; off; off >>= 1) sum += __shfl_xor(sum, off);
  Pb[i * 64 + lane] = f2b(e / sum);
}

// ---------------- O^T = (P @ V)^T, bf16, (B, HW, 384) ------------------------
// v3: V-tile (48 x 256, 24 KB) LDS-staged with coalesced us8 global loads +
// ds_write_b128; B-fragments built from LDS (ds_read_u16, <=2-way bank
// aliasing with 260-elem row pad = free). Kills the 64-per-thread scalar 2B
// GLOBAL gathers (128B useful per 1024B instr) that dominated this kernel.
__global__ __launch_bounds__(256) void k_pv(
    const unsigned short* __restrict__ P, const unsigned short* __restrict__ dwo,
    unsigned short* __restrict__ OT) {
  __shared__ unsigned short Vs[CHD][260];  // raw [k][n_local], pad 260
  int bh = blockIdx.y, b = bh >> 3, h = bh & 7;
  int tid = threadIdx.x;
  int wave = tid >> 6, lane = tid & 63;
  int fm = lane & 15, fq = lane >> 4;
  const unsigned short* Pb = P + (long)bh * CHD * 64;
  const unsigned short* V = dwo + ((long)b * C3 + 2 * DIMC + h * CHD) * HW;
  int n0blk = blockIdx.x * 256;

  // stage V[0:48][n0blk:n0blk+256]: 1536 16B-chunks, 6 per thread, coalesced
#pragma unroll
  for (int i = 0; i < 6; ++i) {
    int c = tid + i * 256;          // 0..1535
    int kk = c >> 5;                // 0..47
    int jc = (c & 31) * 8;          // 0..248
    *(us8*)(&Vs[kk][jc]) = *(const us8*)(V + (long)kk * HW + n0blk + jc);
  }

  bf16x8 a0[3], a1[3];
#pragma unroll
  for (int t = 0; t < 3; ++t) {
    a0[t] = *(const bf16x8*)(Pb + (t * 16 + fm) * 64 + fq * 8);
    a1[t] = *(const bf16x8*)(Pb + (t * 16 + fm) * 64 + 32 + fq * 8);
  }
  __syncthreads();

  unsigned short* OTb = OT + (long)b * HW * DIMC;
  for (int nt = 0; nt < 4; ++nt) {
    int nl = wave * 64 + nt * 16 + fm;  // local n, 0..255
    bf16x8 b0, b1;
#pragma unroll
    for (int j = 0; j < 8; ++j) {
      ((unsigned short*)&b0)[j] = Vs[fq * 8 + j][nl];
      int kk1 = 32 + fq * 8 + j;
      ((unsigned short*)&b1)[j] = (kk1 < CHD) ? Vs[kk1][nl] : (unsigned short)0;
    }
    f32x4 acc[3] = {};
#pragma unroll
    for (int t = 0; t < 3; ++t) {
      acc[t] = __builtin_amdgcn_mfma_f32_16x16x32_bf16(a0[t], b0, acc[t], 0, 0, 0);
      acc[t] = __builtin_amdgcn_mfma_f32_16x16x32_bf16(a1[t], b1, acc[t], 0, 0, 0);
    }
    int n = n0blk + nl;
#pragma unroll
    for (int t = 0; t < 3; ++t) {
      int cg = h * CHD + t * 16 + fq * 4;
      us4 st;
#pragma unroll
      for (int r = 0; r < 4; ++r) st[r] = f2b(acc[t][r]);
      *(us4*)(OTb + (long)n * DIMC + cg) = st;
    }
  }
}

extern "C" void kernel_launch(void* const* d_in, const int* in_sizes, int n_in,
                              void* d_out, int out_size, void* d_ws, size_t ws_size,
                              hipStream_t stream) {
  const float* x = (const float*)d_in[0];
  const float* qkv_w = (const float*)d_in[1];
  const float* dw_w = (const float*)d_in[2];
  const float* proj_w = (const float*)d_in[3];
  const float* temp = (const float*)d_in[4];
  const float* u_qkv = (const float*)d_in[5];
  const float* u_dw = (const float*)d_in[6];
  const float* u_proj = (const float*)d_in[7];
  float* out = (float*)d_out;

  char* ws = (char*)d_ws;
  size_t cur = 0;
  auto take = [&](size_t n) { size_t r = cur; cur += (n + 255) & ~(size_t)255; return r; };
  // power-iteration scratch: t0 | t1 | t2 | sig2 contiguous -> one memset
  float* t0 = (float*)(ws + take(DIMC * 4));        // 384
  float* t1 = (float*)(ws + take(16 * 4));          // 9 (padded)
  float* t2 = (float*)(ws + take(DIMC * 4));        // 384
  float* sig2 = (float*)(ws + take(4 * 4));         // 3
  size_t tbytes = cur;                              // all of the above
  float* scales = (float*)(ws + take(3 * 4));
  float* sumsq = (float*)(ws + take((size_t)BATCH * 2 * DIMC * 4));
  float* S = (float*)(ws + take((size_t)32 * CHD * CHD * 4));
  unsigned short* P = (unsigned short*)(ws + take((size_t)32 * CHD * 64 * 2));
  unsigned short* wq = (unsigned short*)(ws + take((size_t)C3 * DIMC * 2));
  unsigned short* wp = (unsigned short*)(ws + take((size_t)DIMC * DIMC * 2));
  float* wd = (float*)(ws + take((size_t)C3 * 9 * 4));
  unsigned short* xT = (unsigned short*)(ws + take((size_t)BATCH * HW * DIMC * 2));
  unsigned short* qkv = (unsigned short*)(ws + take((size_t)BATCH * C3 * HW * 2));
  unsigned short* dwo = (unsigned short*)(ws + take((size_t)BATCH * C3 * HW * 2));
  unsigned short* OT = xT;  // xT is dead after gemm1; reuse for O^T

  hipMemsetAsync(ws, 0, tbytes, stream);  // t0,t1,t2,sig2
  hipMemsetAsync(sumsq, 0, (size_t)BATCH * 2 * DIMC * 4, stream);
  hipMemsetAsync(S, 0, (size_t)32 * CHD * CHD * 4, stream);

  k_wtu<<<dim3(9, 2), dim3(384), 0, stream>>>(qkv_w, proj_w, u_qkv, u_proj, t0, t2);
  k_wtu_dw<<<dim3(1), dim3(256), 0, stream>>>(dw_w, u_dw, t1);
  k_wv<<<dim3(288, 3), dim3(256), 0, stream>>>(qkv_w, dw_w, proj_w, t0, t1, t2, sig2);
  k_scale<<<dim3(1), dim3(256), 0, stream>>>(t0, t1, t2, sig2, scales);
  k_prep<<<dim3((C3 * DIMC + 255) / 256), dim3(256), 0, stream>>>(qkv_w, dw_w, proj_w, scales, wq, wp, wd);
  k_transpose<<<dim3(HW / 32, DIMC / 64, BATCH), dim3(256), 0, stream>>>(x, xT);
  gemm128<true><<<dim3(HW / 128, C3 / 128, BATCH), dim3(256), 0, stream>>>(
      wq, xT, qkv, (long)HW * DIMC, (long)C3 * HW);
  k_dwconv<<<dim3(C3, BATCH), dim3(256), 0, stream>>>(qkv, wd, dwo, sumsq);
  k_qk<<<dim3(32, 32), dim3(256), 0, stream>>>(dwo, S);
  k_softmax<<<dim3(12, 32), dim3(256), 0, stream>>>(S, sumsq, temp, P);
  k_pv<<<dim3(64, 32), dim3(256), 0, stream>>>(P, dwo, OT);
  gemm128<false><<<dim3(HW / 128, DIMC / 128, BATCH), dim3(256), 0, stream>>>(
      wp, OT, out, (long)HW * DIMC, (long)DIMC * HW);
}